// Round 12
// baseline (116.632 us; speedup 1.0000x reference)
//
#include <hip/hip_runtime.h>
#include <math.h>

#define BATCH 64
#define T 4096
#define ALPH 32
#define NS 128
#define MB 16              // batches per block (MFMA M)
#define NGRP 4             // BATCH/MB
#define NCHUNK 512
#define CL 8               // T/NCHUNK
#define WARM 4
#define NTOKF (CL + WARM)  // 12 — fixed fetch count, valid for every chunk

typedef __bf16 bf16x8 __attribute__((ext_vector_type(8)));
typedef short  short8 __attribute__((ext_vector_type(8)));
typedef float  f32x4  __attribute__((ext_vector_type(4)));

// ws layout (float offsets):
//   frag : ushort, 32 frags * 1024 B = 32 KB   at 0      (B-operand fragments of A)
//   Bme  : ushort[32][128] e-major bf16 (8 KB) at 8192   (Bme[tk][c*8+nt] = Bm[tk][nt*16+c])
//   I    : float[128], permuted storage order  at 10240
//   tok  : uchar[BATCH*T] (256 KB)             at 10368
#define WS_FRAG 0
#define WS_BME  8192
#define WS_I    10240
#define WS_TOK_F 10368

static __device__ inline unsigned short f2u(float f) {
    __bf16 b = (__bf16)f;
    return __builtin_bit_cast(unsigned short, b);
}

// Storage permutation for alpha/I: storage slot p holds logical state
//   n(p) = ((p>>5)*2 + (p&1))*16 + ((p>>1)&15)
// C/D writes pack as dword pairs; A-operand reads are contiguous b128.

// ---------------- prep ----------------
// blocks [0,1024): token extraction (one coalesced 33.5 MB pass);
// blocks [1024,1152): A-row softmax + frag pack;
// block 1152: Bm column softmax (e-major bf16) + I softmax + zero d_out.
__global__ __launch_bounds__(256) void prep_kernel(const float* __restrict__ onehot,
                                                   const float* __restrict__ A_logits,
                                                   const float* __restrict__ B_logits,
                                                   const float* __restrict__ I_logits,
                                                   float* __restrict__ ws,
                                                   float* __restrict__ out,
                                                   unsigned char* __restrict__ tok) {
    unsigned short* frag = (unsigned short*)(ws + WS_FRAG);
    unsigned short* Bme  = (unsigned short*)(ws + WS_BME);
    float* I_ws = ws + WS_I;
    const int blk = blockIdx.x;
    const int tid = threadIdx.x;

    if (blk < 1024) {
        int b = blk >> 4;
        int t = (blk & 15) * 256 + tid;
        const float4* p = (const float4*)(onehot + ((size_t)b * T + t) * ALPH);
        int tk = 0;
        #pragma unroll
        for (int q = 0; q < 8; ++q) {
            float4 v = p[q];
            if (v.x > 0.5f) tk = 4 * q + 0;
            if (v.y > 0.5f) tk = 4 * q + 1;
            if (v.z > 0.5f) tk = 4 * q + 2;
            if (v.w > 0.5f) tk = 4 * q + 3;
        }
        tok[(size_t)b * T + t] = (unsigned char)tk;
        return;
    }

    if (blk == 1024 + NS) {
        // Bm column softmax -> Bme bf16 e-major; zero out[]
        if (tid < NS) {
            int s = tid;
            float m = -1e30f;
            for (int a = 0; a < ALPH; ++a) m = fmaxf(m, B_logits[a * NS + s]);
            float sum = 0.f;
            for (int a = 0; a < ALPH; ++a) sum += expf(B_logits[a * NS + s] - m);
            float inv = 1.0f / sum;
            int idx = (s & 15) * 8 + (s >> 4);  // c*8 + nt
            for (int a = 0; a < ALPH; ++a)
                Bme[a * NS + idx] = f2u(expf(B_logits[a * NS + s] - m) * inv);
        } else if (tid < NS + BATCH) {
            out[tid - NS] = 0.0f;
        }
        // I softmax
        __shared__ float redm[4];
        __shared__ float reds[4];
        float x = (tid < NS) ? I_logits[tid] : -1e30f;
        float m = x;
        #pragma unroll
        for (int off = 1; off < 64; off <<= 1) m = fmaxf(m, __shfl_xor(m, off));
        int wid = tid >> 6;
        if ((tid & 63) == 0) redm[wid] = m;
        __syncthreads();
        m = fmaxf(fmaxf(redm[0], redm[1]), fmaxf(redm[2], redm[3]));
        float e = (tid < NS) ? expf(x - m) : 0.0f;
        float sg = e;
        #pragma unroll
        for (int off = 1; off < 64; off <<= 1) sg += __shfl_xor(sg, off);
        if ((tid & 63) == 0) reds[wid] = sg;
        __syncthreads();
        float total = (reds[0] + reds[1]) + (reds[2] + reds[3]);
        if (tid < NS) {
            int n = tid;
            int p = (n >> 5) * 32 + (n & 15) * 2 + ((n >> 4) & 1);  // inverse perm
            I_ws[p] = e / total;
        }
        return;
    }

    // A-row softmax, row rho, scattered into MFMA B-fragment layout
    int rho = blk - 1024;
    __shared__ float redm[4];
    __shared__ float reds[4];
    float x = (tid < NS) ? A_logits[rho * NS + tid] : -1e30f;
    float m = x;
    #pragma unroll
    for (int off = 1; off < 64; off <<= 1) m = fmaxf(m, __shfl_xor(m, off));
    int wid = tid >> 6;
    if ((tid & 63) == 0) redm[wid] = m;
    __syncthreads();
    m = fmaxf(fmaxf(redm[0], redm[1]), fmaxf(redm[2], redm[3]));
    float e = (tid < NS) ? expf(x - m) : 0.0f;
    float sg = e;
    #pragma unroll
    for (int off = 1; off < 64; off <<= 1) sg += __shfl_xor(sg, off);
    if ((tid & 63) == 0) reds[wid] = sg;
    __syncthreads();
    float total = (reds[0] + reds[1]) + (reds[2] + reds[3]);
    if (tid < NS) {
        float v = e / total;
        int gamma = tid;
        int kc   = rho >> 5;
        int jlow = (rho >> 4) & 1;
        int quad = (rho >> 2) & 3;
        int j    = (rho & 3) * 2 + jlow;
        int nt   = gamma >> 4;
        int col  = gamma & 15;
        int lane = quad * 16 + col;
        int fid  = kc * 8 + nt;
        frag[fid * 512 + lane * 8 + j] = f2u(v);
    }
}

// ---------------- hmm ----------------
// Block = (batch group g, chunk c), 4 waves split the N dimension: wave w
// owns output states [32w, 32w+32), 8 MFMAs per wave per step, one barrier
// per step, double-buffered bf16 alpha, read-side normalization. CL=8,
// WARM=4: chain 11 steps (7 for c==0); 2048 blocks = 8 blocks/CU = 32
// waves/CU (max occupancy; VGPR 44 <= 64-cap, LDS 17.1 KB*8 <= 160 KB).
// Ledger: chunk c>=1 covers t in [8c, 8c+7] (reset at j=4 normalizes at
// t=8c-1); chunk 0 covers [0,7]. 512*8 = 4096 steps, each exactly once.
__global__ __launch_bounds__(256, 8) void hmm_kernel(const float* __restrict__ ws,
                                                     const unsigned char* __restrict__ tok_g,
                                                     float* __restrict__ out) {
    const unsigned short* Bme_g = (const unsigned short*)(ws + WS_BME);
    const float* I_ws = ws + WS_I;
    const unsigned short* frag_g = (const unsigned short*)(ws + WS_FRAG);

    const int g    = blockIdx.x;
    const int c    = blockIdx.y;
    const int tid  = threadIdx.x;
    const int w    = tid >> 6;       // wave -> states [32w, 32w+32) = nt {2w, 2w+1}
    const int lane = tid & 63;
    const int quad = lane >> 4;
    const int col  = lane & 15;

    __shared__ unsigned short Bme_lds[ALPH * NS];                // 8 KB
    __shared__ __align__(16) short alpha_lds[2][MB * 136];       // bf16 double buffer
    __shared__ unsigned char tok_lds[NTOKF * MB];                // [t][m], 192 B

    const int t0u    = c * CL - WARM;
    const int t0     = (t0u < 0) ? 0 : t0u;
    const bool exact = (t0 == 0);
    const int nsteps = (c + 1) * CL - 1 - t0;   // 7 for c==0, else 11
    const int resetj = c * CL - t0;             // 0 for c==0 (never fires); 4 else

    // stage tokens [t][m] (tiny: 192 B)
    for (int i = tid; i < NTOKF * MB; i += 256)
        tok_lds[i] = tok_g[(size_t)(g * MB + (i & 15)) * T + t0 + (i >> 4)];

    // stage Bme (coalesced dwords)
    {
        const unsigned* src = (const unsigned*)Bme_g;
        unsigned* dst = (unsigned*)Bme_lds;
        #pragma unroll
        for (int i = 0; i < 8; ++i) dst[i * 256 + tid] = src[i * 256 + tid];
    }

    // B-fragments for this wave's nt pair: bfr[kc][b], 32 VGPRs total
    bf16x8 bfr[4][2];
    #pragma unroll
    for (int kc = 0; kc < 4; ++kc)
        #pragma unroll
        for (int b = 0; b < 2; ++b)
            bfr[kc][b] = __builtin_bit_cast(bf16x8,
                *(const short8*)(frag_g + (size_t)(kc * 8 + 2 * w + b) * 512 + lane * 8));

    __syncthreads();

    // initial alpha in storage order: exact chunk I*E0, else uniform
    #pragma unroll
    for (int it = 0; it < 8; ++it) {
        int idx = it * 256 + tid;
        int m = idx >> 7, p = idx & 127;
        float val;
        if (exact) {
            int tk0 = tok_lds[m];
            int nt = ((p >> 5) << 1) + (p & 1);
            int cc = (p >> 1) & 15;
            float bm = (float)__builtin_bit_cast(__bf16, Bme_lds[tk0 * NS + cc * 8 + nt]);
            val = I_ws[p] * bm;
        } else {
            val = 1.0f;
        }
        alpha_lds[0][m * 136 + p] = (short)f2u(val);
    }
    __syncthreads();

    float loglik = 0.0f;  // ledger for batch m=col (uniform across quads/waves)

    for (int j = 1; j <= nsteps; ++j) {
        const int rb = (j + 1) & 1;
        const int wb = j & 1;
        const bool do_norm = ((j & 7) == 0) || (j == resetj);

        // emission dwords (independent of alpha): states (2w)*16+col, (2w+1)*16+col
        unsigned tokp = *(const unsigned*)&tok_lds[j * MB + quad * 4];
        unsigned eu[4];
        #pragma unroll
        for (int r = 0; r < 4; ++r) {
            int tk = (tokp >> (8 * r)) & 255;
            eu[r] = *(const unsigned*)&Bme_lds[tk * NS + col * 8 + 2 * w];
        }

        // A-operand fragments (full K for batch m=col)
        const short* ap = &alpha_lds[rb][col * 136 + quad * 8];
        bf16x8 afr[4];
        #pragma unroll
        for (int kc = 0; kc < 4; ++kc)
            afr[kc] = *(const bf16x8*)(ap + kc * 32);

        f32x4 acc0 = {0.f, 0.f, 0.f, 0.f};
        f32x4 acc1 = {0.f, 0.f, 0.f, 0.f};
        #pragma unroll
        for (int kc = 0; kc < 4; ++kc) {
            acc0 = __builtin_amdgcn_mfma_f32_16x16x32_bf16(afr[kc], bfr[kc][0], acc0, 0, 0, 0);
            acc1 = __builtin_amdgcn_mfma_f32_16x16x32_bf16(afr[kc], bfr[kc][1], acc1, 0, 0, 0);
        }

        float v0[4], v1[4];
        #pragma unroll
        for (int r = 0; r < 4; ++r) {
            float e0 = __builtin_bit_cast(float, eu[r] << 16);
            float e1 = __builtin_bit_cast(float, eu[r] & 0xffff0000u);
            v0[r] = acc0[r] * e0;
            v1[r] = acc1[r] * e1;
        }

        if (do_norm) {
            float asum = 0.f;
            #pragma unroll
            for (int kc = 0; kc < 4; ++kc)
                #pragma unroll
                for (int jj = 0; jj < 8; ++jj) asum += (float)afr[kc][jj];
            asum += __shfl_xor(asum, 16);
            asum += __shfl_xor(asum, 32);       // full mass of batch m=col
            float lg = __logf(asum);
            loglik = (j == resetj) ? 0.0f : (loglik + lg);
            #pragma unroll
            for (int r = 0; r < 4; ++r) {
                float iv = __builtin_amdgcn_rcpf(__shfl(asum, quad * 4 + r));
                v0[r] *= iv;
                v1[r] *= iv;
            }
        }

        // pack (round-half-up, alpha>0) + ONE dword write per r (storage order:
        // states (2w,2w+1)*16+col land at adjacent slots p = w*32 + col*2 + {0,1})
        #pragma unroll
        for (int r = 0; r < 4; ++r) {
            unsigned u0 = __builtin_bit_cast(unsigned, v0[r]) + 0x8000u;
            unsigned u1 = __builtin_bit_cast(unsigned, v1[r]) + 0x8000u;
            unsigned dw = __builtin_amdgcn_perm(u1, u0, 0x07060302u);
            ((unsigned*)&alpha_lds[wb][0])[(quad * 4 + r) * 68 + w * 16 + col] = dw;
        }
        __syncthreads();
    }

    // final flush: out[m] += loglik + log(sum_p alpha_final[m][p])
    {
        const short* ap = &alpha_lds[nsteps & 1][col * 136 + quad * 8];
        float tot = 0.f;
        #pragma unroll
        for (int kc = 0; kc < 4; ++kc) {
            bf16x8 av = *(const bf16x8*)(ap + kc * 32);
            #pragma unroll
            for (int jj = 0; jj < 8; ++jj) tot += (float)av[jj];
        }
        tot += __shfl_xor(tot, 16);
        tot += __shfl_xor(tot, 32);
        if (w == 0 && quad == 0)
            atomicAdd(out + g * MB + col, loglik + __logf(tot));
    }
}

extern "C" void kernel_launch(void* const* d_in, const int* in_sizes, int n_in,
                              void* d_out, int out_size, void* d_ws, size_t ws_size,
                              hipStream_t stream) {
    const float* onehot   = (const float*)d_in[0];
    const float* A_logits = (const float*)d_in[1];
    const float* B_logits = (const float*)d_in[2];
    const float* I_logits = (const float*)d_in[3];
    float* ws  = (float*)d_ws;
    float* out = (float*)d_out;
    unsigned char* tok = (unsigned char*)(ws + WS_TOK_F);

    prep_kernel<<<dim3(1024 + NS + 1), dim3(256), 0, stream>>>(
        onehot, A_logits, B_logits, I_logits, ws, out, tok);
    hmm_kernel<<<dim3(NGRP, NCHUNK), dim3(256), 0, stream>>>(ws, tok, out);
}

// Round 13
// 97.763 us; speedup vs baseline: 1.1930x; 1.1930x over previous
//
#include <hip/hip_runtime.h>
#include <math.h>

#define BATCH 64
#define T 4096
#define ALPH 32
#define NS 128
#define MB 16              // batches per block (MFMA M)
#define NGRP 4             // BATCH/MB
#define NCHUNK 256
#define CL 16              // T/NCHUNK
#define WARM 4
#define NTOKF (CL + WARM)  // 20 — fixed fetch count, valid for every chunk

typedef __bf16 bf16x8 __attribute__((ext_vector_type(8)));
typedef short  short8 __attribute__((ext_vector_type(8)));
typedef float  f32x4  __attribute__((ext_vector_type(4)));

// ws layout (float offsets):
//   frag : ushort, 32 frags * 1024 B = 32 KB   at 0      (B-operand fragments of A)
//   Bme  : ushort[32][128] e-major bf16 (8 KB) at 8192   (Bme[tk][c*8+nt] = Bm[tk][nt*16+c])
//   I    : float[128], permuted storage order  at 10240
//   tok  : uchar[BATCH*T] (256 KB)             at 10368
#define WS_FRAG 0
#define WS_BME  8192
#define WS_I    10240
#define WS_TOK_F 10368

static __device__ inline unsigned short f2u(float f) {
    __bf16 b = (__bf16)f;
    return __builtin_bit_cast(unsigned short, b);
}

// Storage permutation for alpha/I: storage slot p holds logical state
//   n(p) = ((p>>5)*2 + (p&1))*16 + ((p>>1)&15)
// C/D writes pack as dword pairs; A-operand reads are contiguous b128.

// ---------------- prep ----------------
// blocks [0,1024): token extraction (one coalesced 33.5 MB pass);
// blocks [1024,1152): A-row softmax + frag pack;
// block 1152: Bm column softmax (e-major bf16) + I softmax + zero d_out.
__global__ __launch_bounds__(256) void prep_kernel(const float* __restrict__ onehot,
                                                   const float* __restrict__ A_logits,
                                                   const float* __restrict__ B_logits,
                                                   const float* __restrict__ I_logits,
                                                   float* __restrict__ ws,
                                                   float* __restrict__ out,
                                                   unsigned char* __restrict__ tok) {
    unsigned short* frag = (unsigned short*)(ws + WS_FRAG);
    unsigned short* Bme  = (unsigned short*)(ws + WS_BME);
    float* I_ws = ws + WS_I;
    const int blk = blockIdx.x;
    const int tid = threadIdx.x;

    if (blk < 1024) {
        int b = blk >> 4;
        int t = (blk & 15) * 256 + tid;
        const float4* p = (const float4*)(onehot + ((size_t)b * T + t) * ALPH);
        int tk = 0;
        #pragma unroll
        for (int q = 0; q < 8; ++q) {
            float4 v = p[q];
            if (v.x > 0.5f) tk = 4 * q + 0;
            if (v.y > 0.5f) tk = 4 * q + 1;
            if (v.z > 0.5f) tk = 4 * q + 2;
            if (v.w > 0.5f) tk = 4 * q + 3;
        }
        tok[(size_t)b * T + t] = (unsigned char)tk;
        return;
    }

    if (blk == 1024 + NS) {
        // Bm column softmax -> Bme bf16 e-major; zero out[]
        if (tid < NS) {
            int s = tid;
            float m = -1e30f;
            for (int a = 0; a < ALPH; ++a) m = fmaxf(m, B_logits[a * NS + s]);
            float sum = 0.f;
            for (int a = 0; a < ALPH; ++a) sum += expf(B_logits[a * NS + s] - m);
            float inv = 1.0f / sum;
            int idx = (s & 15) * 8 + (s >> 4);  // c*8 + nt
            for (int a = 0; a < ALPH; ++a)
                Bme[a * NS + idx] = f2u(expf(B_logits[a * NS + s] - m) * inv);
        } else if (tid < NS + BATCH) {
            out[tid - NS] = 0.0f;
        }
        // I softmax
        __shared__ float redm[4];
        __shared__ float reds[4];
        float x = (tid < NS) ? I_logits[tid] : -1e30f;
        float m = x;
        #pragma unroll
        for (int off = 1; off < 64; off <<= 1) m = fmaxf(m, __shfl_xor(m, off));
        int wid = tid >> 6;
        if ((tid & 63) == 0) redm[wid] = m;
        __syncthreads();
        m = fmaxf(fmaxf(redm[0], redm[1]), fmaxf(redm[2], redm[3]));
        float e = (tid < NS) ? expf(x - m) : 0.0f;
        float sg = e;
        #pragma unroll
        for (int off = 1; off < 64; off <<= 1) sg += __shfl_xor(sg, off);
        if ((tid & 63) == 0) reds[wid] = sg;
        __syncthreads();
        float total = (reds[0] + reds[1]) + (reds[2] + reds[3]);
        if (tid < NS) {
            int n = tid;
            int p = (n >> 5) * 32 + (n & 15) * 2 + ((n >> 4) & 1);  // inverse perm
            I_ws[p] = e / total;
        }
        return;
    }

    // A-row softmax, row rho, scattered into MFMA B-fragment layout
    int rho = blk - 1024;
    __shared__ float redm[4];
    __shared__ float reds[4];
    float x = (tid < NS) ? A_logits[rho * NS + tid] : -1e30f;
    float m = x;
    #pragma unroll
    for (int off = 1; off < 64; off <<= 1) m = fmaxf(m, __shfl_xor(m, off));
    int wid = tid >> 6;
    if ((tid & 63) == 0) redm[wid] = m;
    __syncthreads();
    m = fmaxf(fmaxf(redm[0], redm[1]), fmaxf(redm[2], redm[3]));
    float e = (tid < NS) ? expf(x - m) : 0.0f;
    float sg = e;
    #pragma unroll
    for (int off = 1; off < 64; off <<= 1) sg += __shfl_xor(sg, off);
    if ((tid & 63) == 0) reds[wid] = sg;
    __syncthreads();
    float total = (reds[0] + reds[1]) + (reds[2] + reds[3]);
    if (tid < NS) {
        float v = e / total;
        int gamma = tid;
        int kc   = rho >> 5;
        int jlow = (rho >> 4) & 1;
        int quad = (rho >> 2) & 3;
        int j    = (rho & 3) * 2 + jlow;
        int nt   = gamma >> 4;
        int col  = gamma & 15;
        int lane = quad * 16 + col;
        int fid  = kc * 8 + nt;
        frag[fid * 512 + lane * 8 + j] = f2u(v);
    }
}

// ---------------- hmm ----------------
// Block = (batch group g, chunk c), 4 waves split the N dimension: wave w
// owns output states [32w, 32w+32), 8 MFMAs per wave per step, one barrier
// per step, double-buffered bf16 alpha, read-side normalization. Tokens come
// precomputed from prep (320 B/block). WARM=4: chain 19 (15 for c==0);
// ledger discard fires at j==resetj==4 (added to the norm cadence).
// NCHUNK=256 is the measured optimum: 512 chunks doubles per-block fixed
// staging cost (+17 us, R12); 64 chunks exposes chain latency (R4).
__global__ __launch_bounds__(256, 4) void hmm_kernel(const float* __restrict__ ws,
                                                     const unsigned char* __restrict__ tok_g,
                                                     float* __restrict__ out) {
    const unsigned short* Bme_g = (const unsigned short*)(ws + WS_BME);
    const float* I_ws = ws + WS_I;
    const unsigned short* frag_g = (const unsigned short*)(ws + WS_FRAG);

    const int g    = blockIdx.x;
    const int c    = blockIdx.y;
    const int tid  = threadIdx.x;
    const int w    = tid >> 6;       // wave -> states [32w, 32w+32) = nt {2w, 2w+1}
    const int lane = tid & 63;
    const int quad = lane >> 4;
    const int col  = lane & 15;

    __shared__ unsigned short Bme_lds[ALPH * NS];                // 8 KB
    __shared__ __align__(16) short alpha_lds[2][MB * 136];       // bf16 double buffer
    __shared__ unsigned char tok_lds[NTOKF * MB];                // [t][m], 320 B

    const int t0u    = c * CL - WARM;
    const int t0     = (t0u < 0) ? 0 : t0u;
    const bool exact = (t0 == 0);
    const int nsteps = (c + 1) * CL - 1 - t0;   // 15 for c==0, else 19
    const int resetj = c * CL - t0;             // 0 for c==0 (never fires); 4 else

    // stage tokens [t][m] (tiny: 320 B)
    for (int i = tid; i < NTOKF * MB; i += 256)
        tok_lds[i] = tok_g[(size_t)(g * MB + (i & 15)) * T + t0 + (i >> 4)];

    // stage Bme (coalesced dwords)
    {
        const unsigned* src = (const unsigned*)Bme_g;
        unsigned* dst = (unsigned*)Bme_lds;
        #pragma unroll
        for (int i = 0; i < 8; ++i) dst[i * 256 + tid] = src[i * 256 + tid];
    }

    // B-fragments for this wave's nt pair: bfr[kc][b], 32 VGPRs total
    bf16x8 bfr[4][2];
    #pragma unroll
    for (int kc = 0; kc < 4; ++kc)
        #pragma unroll
        for (int b = 0; b < 2; ++b)
            bfr[kc][b] = __builtin_bit_cast(bf16x8,
                *(const short8*)(frag_g + (size_t)(kc * 8 + 2 * w + b) * 512 + lane * 8));

    __syncthreads();

    // initial alpha in storage order: exact chunk I*E0, else uniform
    #pragma unroll
    for (int it = 0; it < 8; ++it) {
        int idx = it * 256 + tid;
        int m = idx >> 7, p = idx & 127;
        float val;
        if (exact) {
            int tk0 = tok_lds[m];
            int nt = ((p >> 5) << 1) + (p & 1);
            int cc = (p >> 1) & 15;
            float bm = (float)__builtin_bit_cast(__bf16, Bme_lds[tk0 * NS + cc * 8 + nt]);
            val = I_ws[p] * bm;
        } else {
            val = 1.0f;
        }
        alpha_lds[0][m * 136 + p] = (short)f2u(val);
    }
    __syncthreads();

    float loglik = 0.0f;  // ledger for batch m=col (uniform across quads/waves)

    for (int j = 1; j <= nsteps; ++j) {
        const int rb = (j + 1) & 1;
        const int wb = j & 1;
        const bool do_norm = ((j & 7) == 0) || (j == resetj);

        // emission dwords (independent of alpha): states (2w)*16+col, (2w+1)*16+col
        unsigned tokp = *(const unsigned*)&tok_lds[j * MB + quad * 4];
        unsigned eu[4];
        #pragma unroll
        for (int r = 0; r < 4; ++r) {
            int tk = (tokp >> (8 * r)) & 255;
            eu[r] = *(const unsigned*)&Bme_lds[tk * NS + col * 8 + 2 * w];
        }

        // A-operand fragments (full K for batch m=col)
        const short* ap = &alpha_lds[rb][col * 136 + quad * 8];
        bf16x8 afr[4];
        #pragma unroll
        for (int kc = 0; kc < 4; ++kc)
            afr[kc] = *(const bf16x8*)(ap + kc * 32);

        f32x4 acc0 = {0.f, 0.f, 0.f, 0.f};
        f32x4 acc1 = {0.f, 0.f, 0.f, 0.f};
        #pragma unroll
        for (int kc = 0; kc < 4; ++kc) {
            acc0 = __builtin_amdgcn_mfma_f32_16x16x32_bf16(afr[kc], bfr[kc][0], acc0, 0, 0, 0);
            acc1 = __builtin_amdgcn_mfma_f32_16x16x32_bf16(afr[kc], bfr[kc][1], acc1, 0, 0, 0);
        }

        float v0[4], v1[4];
        #pragma unroll
        for (int r = 0; r < 4; ++r) {
            float e0 = __builtin_bit_cast(float, eu[r] << 16);
            float e1 = __builtin_bit_cast(float, eu[r] & 0xffff0000u);
            v0[r] = acc0[r] * e0;
            v1[r] = acc1[r] * e1;
        }

        if (do_norm) {
            float asum = 0.f;
            #pragma unroll
            for (int kc = 0; kc < 4; ++kc)
                #pragma unroll
                for (int jj = 0; jj < 8; ++jj) asum += (float)afr[kc][jj];
            asum += __shfl_xor(asum, 16);
            asum += __shfl_xor(asum, 32);       // full mass of batch m=col
            float lg = __logf(asum);
            loglik = (j == resetj) ? 0.0f : (loglik + lg);
            #pragma unroll
            for (int r = 0; r < 4; ++r) {
                float iv = __builtin_amdgcn_rcpf(__shfl(asum, quad * 4 + r));
                v0[r] *= iv;
                v1[r] *= iv;
            }
        }

        // pack (round-half-up, alpha>0) + ONE dword write per r (storage order:
        // states (2w,2w+1)*16+col land at adjacent slots p = w*32 + col*2 + {0,1})
        #pragma unroll
        for (int r = 0; r < 4; ++r) {
            unsigned u0 = __builtin_bit_cast(unsigned, v0[r]) + 0x8000u;
            unsigned u1 = __builtin_bit_cast(unsigned, v1[r]) + 0x8000u;
            unsigned dw = __builtin_amdgcn_perm(u1, u0, 0x07060302u);
            ((unsigned*)&alpha_lds[wb][0])[(quad * 4 + r) * 68 + w * 16 + col] = dw;
        }
        __syncthreads();
    }

    // final flush: out[m] += loglik + log(sum_p alpha_final[m][p])
    {
        const short* ap = &alpha_lds[nsteps & 1][col * 136 + quad * 8];
        float tot = 0.f;
        #pragma unroll
        for (int kc = 0; kc < 4; ++kc) {
            bf16x8 av = *(const bf16x8*)(ap + kc * 32);
            #pragma unroll
            for (int jj = 0; jj < 8; ++jj) tot += (float)av[jj];
        }
        tot += __shfl_xor(tot, 16);
        tot += __shfl_xor(tot, 32);
        if (w == 0 && quad == 0)
            atomicAdd(out + g * MB + col, loglik + __logf(tot));
    }
}

extern "C" void kernel_launch(void* const* d_in, const int* in_sizes, int n_in,
                              void* d_out, int out_size, void* d_ws, size_t ws_size,
                              hipStream_t stream) {
    const float* onehot   = (const float*)d_in[0];
    const float* A_logits = (const float*)d_in[1];
    const float* B_logits = (const float*)d_in[2];
    const float* I_logits = (const float*)d_in[3];
    float* ws  = (float*)d_ws;
    float* out = (float*)d_out;
    unsigned char* tok = (unsigned char*)(ws + WS_TOK_F);

    prep_kernel<<<dim3(1024 + NS + 1), dim3(256), 0, stream>>>(
        onehot, A_logits, B_logits, I_logits, ws, out, tok);
    hmm_kernel<<<dim3(NGRP, NCHUNK), dim3(256), 0, stream>>>(ws, tok, out);
}